// Round 1
// baseline (195.225 us; speedup 1.0000x reference)
//
#include <hip/hip_runtime.h>

// Until operator: r[t] = max( min(1,psi[t]), min(phi[t], r[t+1]) ), r[T] = -inf.
// f(x)=max(a,min(b,x)) closed under composition (f earlier in time):
//   (f o g): A = max(a_f, min(b_f, a_g)), B = min(b_f, b_g)
// float4 = 2 timesteps x 2 channels = one "pair entry". Row = 4096 entries.
// block = one row (8 waves); wave = contiguous 512-entry segment.
//
// R5 structural change vs R4: the two 256-entry rounds now share ONE
// 1024-float wave-private LDS region (build G -> fence -> transposed read,
// round-sequential), instead of staging both rounds at once. LDS per block
// 64.5KB -> 32.5KB: occupancy 2 -> 4 blocks/CU (2048 threads/CU = HW max).
// Global loads split per-round (8+8) to stay under the 64-VGPR cap implied
// by __launch_bounds__(512, 8). All reuse hazards are wave-private WAR,
// covered by wave-level fences; still only ONE real barrier (ssum).

#define T_LEN 8192
#define NSEG  8            // waves per block = segments per row
#define BLOCK (NSEG * 64)  // 512

__device__ __forceinline__ float rfl(float x) {
    return __int_as_float(__builtin_amdgcn_readfirstlane(__float_as_int(x)));
}

// Wave-level ordering fence for wave-private LDS reuse: prevents the compiler
// from moving LDS accesses across it; HW executes a wave's DS ops in order.
__device__ __forceinline__ void wave_lds_fence() {
    __asm__ volatile("" ::: "memory");
    __builtin_amdgcn_wave_barrier();
    __asm__ volatile("" ::: "memory");
}

__global__ __launch_bounds__(BLOCK, 8) void until_kernel(
    const float* __restrict__ phi, const float* __restrict__ psi,
    float* __restrict__ out)
{
    const int  row  = blockIdx.x;
    const int  tid  = threadIdx.x;
    const int  w    = tid >> 6;
    const int  lane = tid & 63;
    const float NEG = -__builtin_huge_valf();
    const float POS =  __builtin_huge_valf();

    const size_t segf4 = (size_t)row * (T_LEN / 2) + (size_t)w * 512;
    const float4* __restrict__ phi4 = (const float4*)phi + segf4;
    const float4* __restrict__ psi4 = (const float4*)psi + segf4;
    float4* __restrict__ out4 = (float4*)out + segf4;

    // Per-wave private 1024-float region, time-multiplexed:
    //   round r G phase: 4 SoA comps x 256 entries (GAx/GAy/GBx/GBy)
    //   carry phase:     CX[e] at wl[e], CY[e] at wl[512+e]
    __shared__ alignas(16) float lds[NSEG * 1024];
    __shared__ float4 ssum[NSEG];
    float* wl = lds + w * 1024;

    float4 GAx[2], GAy[2], GBx[2], GBy[2];
    float  Sax[2], Say[2], Sbx[2], Sby[2];

#pragma unroll
    for (int r = 0; r < 2; ++r) {
        if (r) wave_lds_fence();   // WAR: round-0 transposed reads done first

        // ---- per-round burst: 8 global loads back-to-back ----
        float4 P[4], Q[4];
#pragma unroll
        for (int kl = 0; kl < 4; ++kl) {
            P[kl] = phi4[(r * 4 + kl) * 64 + lane];
            Q[kl] = psi4[(r * 4 + kl) * 64 + lane];
        }

        // ---- build pair functions G, SoA write (dense, conflict-free) ----
#pragma unroll
        for (int kl = 0; kl < 4; ++kl) {
            float* base = wl + kl * 64 + lane;
            float v0x = fminf(1.f, Q[kl].x), v0y = fminf(1.f, Q[kl].y);
            float v1x = fminf(1.f, Q[kl].z), v1y = fminf(1.f, Q[kl].w);
            base[0]   = fmaxf(v0x, fminf(P[kl].x, v1x));  // GAx
            base[256] = fmaxf(v0y, fminf(P[kl].y, v1y));  // GAy
            base[512] = fminf(P[kl].x, P[kl].z);          // GBx
            base[768] = fminf(P[kl].y, P[kl].w);          // GBy
        }
        wave_lds_fence();   // wave-private transpose: no block barrier needed

        // ---- transposed read (b128, dense) + compose + suffix scan ----
        GAx[r] = *(const float4*)(wl + 0 * 256 + lane * 4);
        GAy[r] = *(const float4*)(wl + 1 * 256 + lane * 4);
        GBx[r] = *(const float4*)(wl + 2 * 256 + lane * 4);
        GBy[r] = *(const float4*)(wl + 3 * 256 + lane * 4);

        // local compose right-to-left: H = G_j0 o G_j1 o G_j2 o G_j3
        float hax = GAx[r].w, hay = GAy[r].w, hbx = GBx[r].w, hby = GBy[r].w;
        hax = fmaxf(GAx[r].z, fminf(GBx[r].z, hax));
        hay = fmaxf(GAy[r].z, fminf(GBy[r].z, hay));
        hbx = fminf(GBx[r].z, hbx);
        hby = fminf(GBy[r].z, hby);
        hax = fmaxf(GAx[r].y, fminf(GBx[r].y, hax));
        hay = fmaxf(GAy[r].y, fminf(GBy[r].y, hay));
        hbx = fminf(GBx[r].y, hbx);
        hby = fminf(GBy[r].y, hby);
        hax = fmaxf(GAx[r].x, fminf(GBx[r].x, hax));
        hay = fmaxf(GAy[r].x, fminf(GBy[r].x, hay));
        hbx = fminf(GBx[r].x, hbx);
        hby = fminf(GBy[r].x, hby);

        // 64-lane inclusive SUFFIX scan (toward lane 63)
#pragma unroll
        for (int off = 1; off < 64; off <<= 1) {
            float gax = __shfl_down(hax, off), gay = __shfl_down(hay, off);
            float gbx = __shfl_down(hbx, off), gby = __shfl_down(hby, off);
            bool  val = (lane + off) < 64;
            gax = val ? gax : NEG;  gay = val ? gay : NEG;
            gbx = val ? gbx : POS;  gby = val ? gby : POS;
            hax = fmaxf(hax, fminf(hbx, gax));
            hay = fmaxf(hay, fminf(hby, gay));
            hbx = fminf(hbx, gbx);
            hby = fminf(hby, gby);
        }
        Sax[r] = hax; Say[r] = hay; Sbx[r] = hbx; Sby[r] = hby;
    }

    // ---- segment summary W = R0 o R1 -> ssum (the ONE real barrier) ----
    float R0ax = rfl(Sax[0]), R0ay = rfl(Say[0]);
    float R0bx = rfl(Sbx[0]), R0by = rfl(Sby[0]);
    float R1ax = rfl(Sax[1]), R1ay = rfl(Say[1]);
    float R1bx = rfl(Sbx[1]), R1by = rfl(Sby[1]);
    if (lane == 0) {
        float wax = fmaxf(R0ax, fminf(R0bx, R1ax));
        float way = fmaxf(R0ay, fminf(R0by, R1ay));
        float wbx = fminf(R0bx, R1bx);
        float wby = fminf(R0by, R1by);
        ssum[w] = make_float4(wax, way, wbx, wby);
    }
    __syncthreads();
    float rcx = NEG, rcy = NEG;   // carry entering this segment's right edge
    for (int j = NSEG - 1; j > w; --j) {
        float4 s = ssum[j];
        rcx = fmaxf(s.x, fminf(s.z, rcx));
        rcy = fmaxf(s.y, fminf(s.w, rcy));
    }

    // carries entering each round (round 0 sees round 1 applied first)
    float rinx[2], riny[2];
    rinx[1] = rcx;
    riny[1] = rcy;
    rinx[0] = fmaxf(R1ax, fminf(R1bx, rcx));
    riny[0] = fmaxf(R1ay, fminf(R1by, rcy));

    // ---- per-entry carries -> wave-private LDS (b128, dense) ----
    wave_lds_fence();   // WAR: round-1 transposed reads before overwrite
#pragma unroll
    for (int r = 0; r < 2; ++r) {
        // y = value at lane's LEFT edge = S_r[lane](r_in)
        float yx = fmaxf(Sax[r], fminf(Sbx[r], rinx[r]));
        float yy = fmaxf(Say[r], fminf(Sby[r], riny[r]));
        // carry entering lane's rightmost entry = y_{lane+1} (lane63: r_in)
        float cx = __shfl_down(yx, 1), cy = __shfl_down(yy, 1);
        if (lane == 63) { cx = rinx[r]; cy = riny[r]; }
        float4 CX, CY;
        CX.w = cx;
        CY.w = cy;
        CX.z = fmaxf(GAx[r].w, fminf(GBx[r].w, CX.w));
        CY.z = fmaxf(GAy[r].w, fminf(GBy[r].w, CY.w));
        CX.y = fmaxf(GAx[r].z, fminf(GBx[r].z, CX.z));
        CY.y = fmaxf(GAy[r].z, fminf(GBy[r].z, CY.z));
        CX.x = fmaxf(GAx[r].y, fminf(GBx[r].y, CX.y));
        CY.x = fmaxf(GAy[r].y, fminf(GBy[r].y, CY.y));
        *(float4*)(wl +       r * 256 + lane * 4) = CX;  // CX[e] at wl[e]
        *(float4*)(wl + 512 + r * 256 + lane * 4) = CY;  // CY[e] at wl[512+e]
    }
    wave_lds_fence();   // wave-private carry handoff: no block barrier

    // ---- emit outputs: coalesced reload (L2/L3-warm) + carry from LDS ----
#pragma unroll
    for (int k = 0; k < 8; ++k) {
        const int e = k * 64 + lane;
        float4 P2 = phi4[e];
        float4 Q2 = psi4[e];
        float cx = wl[e];          // r at this entry's right edge
        float cy = wl[512 + e];
        float r1x = fmaxf(fminf(1.f, Q2.z), fminf(P2.z, cx));
        float r1y = fmaxf(fminf(1.f, Q2.w), fminf(P2.w, cy));
        float r0x = fmaxf(fminf(1.f, Q2.x), fminf(P2.x, r1x));
        float r0y = fmaxf(fminf(1.f, Q2.y), fminf(P2.y, r1y));
        out4[e] = make_float4(r0x, r0y, r1x, r1y);
    }
}

extern "C" void kernel_launch(void* const* d_in, const int* in_sizes, int n_in,
                              void* d_out, int out_size, void* d_ws, size_t ws_size,
                              hipStream_t stream) {
    const float* phi = (const float*)d_in[0];
    const float* psi = (const float*)d_in[1];
    float* out = (float*)d_out;
    const int Bn = in_sizes[0] / (T_LEN * 2);  // = 1024
    until_kernel<<<Bn, BLOCK, 0, stream>>>(phi, psi, out);
}

// Round 2
// 174.636 us; speedup vs baseline: 1.1179x; 1.1179x over previous
//
#include <hip/hip_runtime.h>

// Until operator: r[t] = max( min(1,psi[t]), min(phi[t], r[t+1]) ), r[T] = -inf.
// f(x)=max(a,min(b,x)) closed under composition (f earlier in time):
//   (f o g): A = max(a_f, min(b_f, a_g)), B = min(b_f, b_g)
// float4 = 2 timesteps x 2 channels = one "pair entry". Row = 4096 entries.
// block = one row (8 waves); wave = contiguous 512-entry segment.
//
// R6 vs R4: the emit-phase global RELOAD of phi/psi is deleted. The loader
// lane of entry e (= k*64+lane) is also its emitter, so P and V=min(1,psi)
// stay in registers across the whole kernel (64 VGPRs held); only carries
// cross lanes (via wave-private LDS, as before). Removes 16 vmem instrs per
// thread (40% of vmem issue slots) + the L2-latency chain at each block's
// tail. launch_bounds(512,4) -> VGPR cap 128 (peak live ~120, no spill);
// LDS 64.5KB still caps occupancy at 2 blocks/CU, so VGPR growth is free.
// (R5 post-mortem: launch_bounds(512,8) capped VGPR at 32 -> scratch spills
// -> +64MB HBM traffic, 74->90us. Never cap below peak live set.)

#define T_LEN 8192
#define NSEG  8            // waves per block = segments per row
#define BLOCK (NSEG * 64)  // 512

__device__ __forceinline__ float rfl(float x) {
    return __int_as_float(__builtin_amdgcn_readfirstlane(__float_as_int(x)));
}

// Wave-level ordering fence for wave-private LDS reuse: prevents the compiler
// from moving LDS accesses across it; HW executes a wave's DS ops in order.
__device__ __forceinline__ void wave_lds_fence() {
    __asm__ volatile("" ::: "memory");
    __builtin_amdgcn_wave_barrier();
    __asm__ volatile("" ::: "memory");
}

__global__ __launch_bounds__(BLOCK, 4) void until_kernel(
    const float* __restrict__ phi, const float* __restrict__ psi,
    float* __restrict__ out)
{
    const int  row  = blockIdx.x;
    const int  tid  = threadIdx.x;
    const int  w    = tid >> 6;
    const int  lane = tid & 63;
    const float NEG = -__builtin_huge_valf();
    const float POS =  __builtin_huge_valf();

    const size_t segf4 = (size_t)row * (T_LEN / 2) + (size_t)w * 512;
    const float4* __restrict__ phi4 = (const float4*)phi + segf4;
    const float4* __restrict__ psi4 = (const float4*)psi + segf4;
    float4* __restrict__ out4 = (float4*)out + segf4;

    // Per-wave private 2048-float region:
    //   G phase:  round r in [r*1024, r*1024+1024): 4 SoA comps x 256 entries
    //   carry phase (reuses round-0 area): CX[e] at wl[e], CY[e] at wl[512+e]
    __shared__ alignas(16) float lds[NSEG * 2048];
    __shared__ float4 ssum[NSEG];
    float* wl = lds + w * 2048;

    // ---- burst: issue all 16 global loads back-to-back ----
    // P = phi raw; V = min(1, psi) folded at load (psi raw never needed again)
    float4 P[8], V[8];
#pragma unroll
    for (int k = 0; k < 8; ++k) {
        P[k] = phi4[k * 64 + lane];
        V[k] = psi4[k * 64 + lane];
    }
#pragma unroll
    for (int k = 0; k < 8; ++k) {
        V[k].x = fminf(1.f, V[k].x);
        V[k].y = fminf(1.f, V[k].y);
        V[k].z = fminf(1.f, V[k].z);
        V[k].w = fminf(1.f, V[k].w);
    }

    // ---- build pair functions G, SoA write (dense, conflict-free) ----
#pragma unroll
    for (int k = 0; k < 8; ++k) {
        const int r  = k >> 2;
        const int kl = k & 3;
        float* base = wl + r * 1024 + kl * 64 + lane;
        base[0]   = fmaxf(V[k].x, fminf(P[k].x, V[k].z));  // GAx
        base[256] = fmaxf(V[k].y, fminf(P[k].y, V[k].w));  // GAy
        base[512] = fminf(P[k].x, P[k].z);                 // GBx
        base[768] = fminf(P[k].y, P[k].w);                 // GBy
    }
    wave_lds_fence();   // wave-private transpose: no block barrier needed

    // ---- transposed read (b128, dense) + compose + suffix scan per round ----
    float4 GAx[2], GAy[2], GBx[2], GBy[2];
    float  Sax[2], Say[2], Sbx[2], Sby[2];
#pragma unroll
    for (int r = 0; r < 2; ++r) {
        const float* rb = wl + r * 1024;
        GAx[r] = *(const float4*)(rb + 0 * 256 + lane * 4);
        GAy[r] = *(const float4*)(rb + 1 * 256 + lane * 4);
        GBx[r] = *(const float4*)(rb + 2 * 256 + lane * 4);
        GBy[r] = *(const float4*)(rb + 3 * 256 + lane * 4);

        // local compose right-to-left: H = G_j0 o G_j1 o G_j2 o G_j3
        float hax = GAx[r].w, hay = GAy[r].w, hbx = GBx[r].w, hby = GBy[r].w;
        hax = fmaxf(GAx[r].z, fminf(GBx[r].z, hax));
        hay = fmaxf(GAy[r].z, fminf(GBy[r].z, hay));
        hbx = fminf(GBx[r].z, hbx);
        hby = fminf(GBy[r].z, hby);
        hax = fmaxf(GAx[r].y, fminf(GBx[r].y, hax));
        hay = fmaxf(GAy[r].y, fminf(GBy[r].y, hay));
        hbx = fminf(GBx[r].y, hbx);
        hby = fminf(GBy[r].y, hby);
        hax = fmaxf(GAx[r].x, fminf(GBx[r].x, hax));
        hay = fmaxf(GAy[r].x, fminf(GBy[r].x, hay));
        hbx = fminf(GBx[r].x, hbx);
        hby = fminf(GBy[r].x, hby);

        // 64-lane inclusive SUFFIX scan (toward lane 63)
#pragma unroll
        for (int off = 1; off < 64; off <<= 1) {
            float gax = __shfl_down(hax, off), gay = __shfl_down(hay, off);
            float gbx = __shfl_down(hbx, off), gby = __shfl_down(hby, off);
            bool  val = (lane + off) < 64;
            gax = val ? gax : NEG;  gay = val ? gay : NEG;
            gbx = val ? gbx : POS;  gby = val ? gby : POS;
            hax = fmaxf(hax, fminf(hbx, gax));
            hay = fmaxf(hay, fminf(hby, gay));
            hbx = fminf(hbx, gbx);
            hby = fminf(hby, gby);
        }
        Sax[r] = hax; Say[r] = hay; Sbx[r] = hbx; Sby[r] = hby;
    }

    // ---- segment summary W = R0 o R1 -> ssum (the ONE real barrier) ----
    float R0ax = rfl(Sax[0]), R0ay = rfl(Say[0]);
    float R0bx = rfl(Sbx[0]), R0by = rfl(Sby[0]);
    float R1ax = rfl(Sax[1]), R1ay = rfl(Say[1]);
    float R1bx = rfl(Sbx[1]), R1by = rfl(Sby[1]);
    if (lane == 0) {
        float wax = fmaxf(R0ax, fminf(R0bx, R1ax));
        float way = fmaxf(R0ay, fminf(R0by, R1ay));
        float wbx = fminf(R0bx, R1bx);
        float wby = fminf(R0by, R1by);
        ssum[w] = make_float4(wax, way, wbx, wby);
    }
    __syncthreads();
    float rcx = NEG, rcy = NEG;   // carry entering this segment's right edge
    for (int j = NSEG - 1; j > w; --j) {
        float4 s = ssum[j];
        rcx = fmaxf(s.x, fminf(s.z, rcx));
        rcy = fmaxf(s.y, fminf(s.w, rcy));
    }

    // carries entering each round (round 0 sees round 1 applied first)
    float rinx[2], riny[2];
    rinx[1] = rcx;
    riny[1] = rcy;
    rinx[0] = fmaxf(R1ax, fminf(R1bx, rcx));
    riny[0] = fmaxf(R1ay, fminf(R1by, rcy));

    // ---- per-entry carries -> wave-private LDS (b128, dense) ----
#pragma unroll
    for (int r = 0; r < 2; ++r) {
        // y = value at lane's LEFT edge = S_r[lane](r_in)
        float yx = fmaxf(Sax[r], fminf(Sbx[r], rinx[r]));
        float yy = fmaxf(Say[r], fminf(Sby[r], riny[r]));
        // carry entering lane's rightmost entry = y_{lane+1} (lane63: r_in)
        float cx = __shfl_down(yx, 1), cy = __shfl_down(yy, 1);
        if (lane == 63) { cx = rinx[r]; cy = riny[r]; }
        float4 CX, CY;
        CX.w = cx;
        CY.w = cy;
        CX.z = fmaxf(GAx[r].w, fminf(GBx[r].w, CX.w));
        CY.z = fmaxf(GAy[r].w, fminf(GBy[r].w, CY.w));
        CX.y = fmaxf(GAx[r].z, fminf(GBx[r].z, CX.z));
        CY.y = fmaxf(GAy[r].z, fminf(GBy[r].z, CY.z));
        CX.x = fmaxf(GAx[r].y, fminf(GBx[r].y, CX.y));
        CY.x = fmaxf(GAy[r].y, fminf(GBy[r].y, CY.y));
        *(float4*)(wl +       r * 256 + lane * 4) = CX;  // CX[e] at wl[e]
        *(float4*)(wl + 512 + r * 256 + lane * 4) = CY;  // CY[e] at wl[512+e]
    }
    wave_lds_fence();   // wave-private carry handoff: no block barrier

    // ---- emit outputs from REGISTERS (no global reload) + carry from LDS ----
#pragma unroll
    for (int k = 0; k < 8; ++k) {
        const int e = k * 64 + lane;
        float cx = wl[e];          // r at this entry's right edge
        float cy = wl[512 + e];
        float r1x = fmaxf(V[k].z, fminf(P[k].z, cx));
        float r1y = fmaxf(V[k].w, fminf(P[k].w, cy));
        float r0x = fmaxf(V[k].x, fminf(P[k].x, r1x));
        float r0y = fmaxf(V[k].y, fminf(P[k].y, r1y));
        out4[e] = make_float4(r0x, r0y, r1x, r1y);
    }
}

extern "C" void kernel_launch(void* const* d_in, const int* in_sizes, int n_in,
                              void* d_out, int out_size, void* d_ws, size_t ws_size,
                              hipStream_t stream) {
    const float* phi = (const float*)d_in[0];
    const float* psi = (const float*)d_in[1];
    float* out = (float*)d_out;
    const int Bn = in_sizes[0] / (T_LEN * 2);  // = 1024
    until_kernel<<<Bn, BLOCK, 0, stream>>>(phi, psi, out);
}